// Round 1
// baseline (6005.556 us; speedup 1.0000x reference)
//
#include <hip/hip_runtime.h>
#include <hip/hip_bf16.h>
#include <math.h>

#define H_ 16
#define HK_ 64
#define HV_ 64
#define HIDDEN_ 1024
#define BATCH_ 4
#define T_ 2048

__device__ __forceinline__ float wave_sum64(float v) {
  #pragma unroll
  for (int m = 32; m >= 1; m >>= 1) v += __shfl_xor(v, m, 64);
  return v;
}

__device__ __forceinline__ float sigmoidf_(float x) { return 1.f / (1.f + expf(-x)); }
__device__ __forceinline__ float siluf_(float x) { return x / (1.f + expf(-x)); }

// ---------------------------------------------------------------------------
// Simple f32 tiled GEMM: C[M,N] = A[M,K] @ B[K,N] (+ bias[N] if given)
// 64x64 C tile per 256-thread block, 4x4 microtile per thread, K-tiles of 16.
// ---------------------------------------------------------------------------
__global__ __launch_bounds__(256) void gemm_f32(
    const float* __restrict__ A, const float* __restrict__ B,
    const float* __restrict__ bias, float* __restrict__ C,
    int M, int N, int K) {
  __shared__ float As[64][17];
  __shared__ float Bs[16][65];
  const int tx = threadIdx.x % 16;
  const int ty = threadIdx.x / 16;
  const int bm = blockIdx.x * 64;
  const int bn = blockIdx.y * 64;
  float acc[4][4] = {};
  for (int k0 = 0; k0 < K; k0 += 16) {
    #pragma unroll
    for (int i = 0; i < 4; i++) {
      int idx = threadIdx.x + i * 256;           // 0..1023
      int m  = idx / 16, kk = idx % 16;          // A: 64x16
      As[m][kk] = A[(size_t)(bm + m) * K + (k0 + kk)];
      int kk2 = idx / 64, n = idx % 64;          // B: 16x64
      Bs[kk2][n] = (bn + n < N) ? B[(size_t)(k0 + kk2) * N + (bn + n)] : 0.f;
    }
    __syncthreads();
    #pragma unroll
    for (int kk = 0; kk < 16; kk++) {
      float a[4], b[4];
      #pragma unroll
      for (int i = 0; i < 4; i++) a[i] = As[ty * 4 + i][kk];
      #pragma unroll
      for (int j = 0; j < 4; j++) b[j] = Bs[kk][tx * 4 + j];
      #pragma unroll
      for (int i = 0; i < 4; i++)
        #pragma unroll
        for (int j = 0; j < 4; j++) acc[i][j] += a[i] * b[j];
    }
    __syncthreads();
  }
  #pragma unroll
  for (int i = 0; i < 4; i++) {
    #pragma unroll
    for (int j = 0; j < 4; j++) {
      int m = bm + ty * 4 + i, n = bn + tx * 4 + j;
      if (n < N) C[(size_t)m * N + n] = acc[i][j] + (bias ? bias[n] : 0.f);
    }
  }
}

// ---------------------------------------------------------------------------
// Gated delta-rule recurrence, with causal depthwise conv (K=4) + SiLU fused
// as a rolling register window. One wave (64 lanes) per (b,h); lane = v index
// for the state, lane = k index for loading q/k/g. S[:,v] columns are
// independent, so each lane keeps S[0..63][lane] in registers.
// ---------------------------------------------------------------------------
__global__ __launch_bounds__(64) void recurrence(
    const float* __restrict__ qhat, const float* __restrict__ khat,
    const float* __restrict__ vhat, const float* __restrict__ graw,
    const float* __restrict__ braw,
    const float* __restrict__ qcw, const float* __restrict__ qcb,
    const float* __restrict__ kcw, const float* __restrict__ kcb,
    const float* __restrict__ vcw, const float* __restrict__ vcb,
    const float* __restrict__ A_log, const float* __restrict__ dt_bias,
    float* __restrict__ o_out) {
  const int bh = blockIdx.x;            // 0 .. B*H-1
  const int b = bh / H_;
  const int h = bh % H_;
  const int lane = threadIdx.x;         // 0..63
  const int c = h * 64 + lane;

  const float A = expf(A_log[h]);
  const float dtb = dt_bias[c];
  float qw[4], kw[4], vw[4];
  #pragma unroll
  for (int j = 0; j < 4; j++) {
    qw[j] = qcw[c * 4 + j];
    kw[j] = kcw[c * 4 + j];
    vw[j] = vcw[c * 4 + j];
  }
  const float qb = qcb[c], kb = kcb[c], vb = vcb[c];

  float S[64];
  #pragma unroll
  for (int k = 0; k < 64; k++) S[k] = 0.f;

  __shared__ float qn_s[64], kn_s[64], eg_s[64];

  // rolling conv windows (causal pad with zeros)
  float xq0 = 0, xq1 = 0, xq2 = 0;
  float xk0 = 0, xk1 = 0, xk2 = 0;
  float xv0 = 0, xv1 = 0, xv2 = 0;

  const size_t base = ((size_t)b * T_) * HIDDEN_ + c;
  const size_t bbase = ((size_t)b * T_) * H_ + h;

  // prefetch t=0
  float nxq = qhat[base], nxk = khat[base], nxv = vhat[base];
  float ngr = graw[base], nbr = braw[bbase];

  for (int t = 0; t < T_; t++) {
    float xq3 = nxq, xk3 = nxk, xv3 = nxv, gr = ngr, br = nbr;
    if (t + 1 < T_) {
      size_t idx2 = base + (size_t)(t + 1) * HIDDEN_;
      nxq = qhat[idx2]; nxk = khat[idx2]; nxv = vhat[idx2];
      ngr = graw[idx2]; nbr = braw[bbase + (size_t)(t + 1) * H_];
    }

    // fused causal conv + SiLU
    float qv = qb + xq0 * qw[0] + xq1 * qw[1] + xq2 * qw[2] + xq3 * qw[3];
    float kv = kb + xk0 * kw[0] + xk1 * kw[1] + xk2 * kw[2] + xk3 * kw[3];
    float vv = vb + xv0 * vw[0] + xv1 * vw[1] + xv2 * vw[2] + xv3 * vw[3];
    qv = siluf_(qv); kv = siluf_(kv); vv = siluf_(vv);
    xq0 = xq1; xq1 = xq2; xq2 = xq3;
    xk0 = xk1; xk1 = xk2; xk2 = xk3;
    xv0 = xv1; xv1 = xv2; xv2 = xv3;

    // L2 norms over the k-dim (lane plays k-index here)
    float sq = wave_sum64(qv * qv);
    float sk = wave_sum64(kv * kv);
    float qn = qv / (sqrtf(sq) + 1e-6f) * 0.125f;  // HK^-0.5 = 0.125
    float kn = kv / (sqrtf(sk) + 1e-6f);

    // decay gate: exp(-A * softplus(graw + dt_bias))
    float x = gr + dtb;
    float sp = (x > 20.f) ? x : log1pf(expf(x));
    float eg = expf(-A * sp);

    qn_s[lane] = qn; kn_s[lane] = kn; eg_s[lane] = eg;
    __syncthreads();

    float beta = sigmoidf_(br);

    // pass 1: decay state, accumulate kS (lane = v)
    float kS = 0.f;
    #pragma unroll
    for (int k = 0; k < 64; k++) {
      S[k] *= eg_s[k];
      kS += kn_s[k] * S[k];
    }
    float vupd = beta * (vv - kS);
    // pass 2: rank-1 update, accumulate output
    float o = 0.f;
    #pragma unroll
    for (int k = 0; k < 64; k++) {
      S[k] += kn_s[k] * vupd;
      o += qn_s[k] * S[k];
    }
    o_out[base + (size_t)t * HIDDEN_] = o;
    __syncthreads();  // protect LDS before next iteration's writes
  }
}

// ---------------------------------------------------------------------------
// RMS-norm over HV + weight + sigmoid(gate), in-place on o.
// One 64-lane group per (b,t,h).
// ---------------------------------------------------------------------------
__global__ __launch_bounds__(256) void onorm_gate(
    float* __restrict__ o, const float* __restrict__ gate,
    const float* __restrict__ onw, int total_groups) {
  int g = blockIdx.x * (blockDim.x / 64) + threadIdx.x / 64;
  int lane = threadIdx.x % 64;
  if (g >= total_groups) return;
  size_t idx = (size_t)g * 64 + lane;
  float ov = o[idx];
  float ms = wave_sum64(ov * ov) * (1.f / 64.f);
  float r = rsqrtf(ms + 1e-5f);
  o[idx] = ov * r * onw[lane] * sigmoidf_(gate[idx]);
}

extern "C" void kernel_launch(void* const* d_in, const int* in_sizes, int n_in,
                              void* d_out, int out_size, void* d_ws, size_t ws_size,
                              hipStream_t stream) {
  const float* hs    = (const float*)d_in[0];
  const float* Wq    = (const float*)d_in[1];
  const float* Wk    = (const float*)d_in[2];
  const float* Wv    = (const float*)d_in[3];
  const float* qcw   = (const float*)d_in[4];
  const float* qcb   = (const float*)d_in[5];
  const float* kcw   = (const float*)d_in[6];
  const float* kcb   = (const float*)d_in[7];
  const float* vcw   = (const float*)d_in[8];
  const float* vcb   = (const float*)d_in[9];
  const float* Wf1   = (const float*)d_in[10];
  const float* Wf2   = (const float*)d_in[11];
  const float* Wb    = (const float*)d_in[12];
  const float* A_log = (const float*)d_in[13];
  const float* dtb   = (const float*)d_in[14];
  const float* Wg1   = (const float*)d_in[15];
  const float* Wg2   = (const float*)d_in[16];
  const float* bg2   = (const float*)d_in[17];
  const float* onw   = (const float*)d_in[18];
  const float* Wo    = (const float*)d_in[19];
  float* out = (float*)d_out;

  const int M = BATCH_ * T_;  // 8192
  char* ws = (char*)d_ws;
  const size_t SZ = (size_t)M * HIDDEN_ * sizeof(float);       // 32 MB
  const size_t SM = (size_t)M * HV_ * sizeof(float);           // 2 MB
  float* qhat = (float*)(ws);
  float* khat = (float*)(ws + SZ);
  float* vhat = (float*)(ws + 2 * SZ);
  float* graw = (float*)(ws + 3 * SZ);
  float* obuf = (float*)(ws + 4 * SZ);
  float* f1   = (float*)(ws + 5 * SZ);
  float* g1   = (float*)(ws + 5 * SZ + SM);
  float* braw = (float*)(ws + 5 * SZ + 2 * SM);
  float* gate = khat;  // reused after the recurrence consumes khat

  dim3 blk(256);
  // projections from hidden_states
  gemm_f32<<<dim3(M / 64, HIDDEN_ / 64), blk, 0, stream>>>(hs, Wq, nullptr, qhat, M, HIDDEN_, HIDDEN_);
  gemm_f32<<<dim3(M / 64, HIDDEN_ / 64), blk, 0, stream>>>(hs, Wk, nullptr, khat, M, HIDDEN_, HIDDEN_);
  gemm_f32<<<dim3(M / 64, HIDDEN_ / 64), blk, 0, stream>>>(hs, Wv, nullptr, vhat, M, HIDDEN_, HIDDEN_);
  gemm_f32<<<dim3(M / 64, 1), blk, 0, stream>>>(hs, Wf1, nullptr, f1, M, HV_, HIDDEN_);
  gemm_f32<<<dim3(M / 64, 1), blk, 0, stream>>>(hs, Wg1, nullptr, g1, M, HV_, HIDDEN_);
  gemm_f32<<<dim3(M / 64, 1), blk, 0, stream>>>(hs, Wb, nullptr, braw, M, H_, HIDDEN_);
  // graw = f1 @ Wf2
  gemm_f32<<<dim3(M / 64, HIDDEN_ / 64), blk, 0, stream>>>(f1, Wf2, nullptr, graw, M, HIDDEN_, HV_);

  // sequential recurrence (conv+silu fused)
  recurrence<<<dim3(BATCH_ * H_), dim3(64), 0, stream>>>(
      qhat, khat, vhat, graw, braw, qcw, qcb, kcw, kcb, vcw, vcb, A_log, dtb, obuf);

  // gate = g1 @ Wg2 + bg2  (into khat's storage, free after recurrence)
  gemm_f32<<<dim3(M / 64, HIDDEN_ / 64), blk, 0, stream>>>(g1, Wg2, bg2, gate, M, HIDDEN_, HV_);

  // RMS-norm + gating, in place on obuf
  int groups = M * H_;
  onorm_gate<<<dim3((groups + 3) / 4), blk, 0, stream>>>(obuf, gate, onw, groups);

  // final projection
  gemm_f32<<<dim3(M / 64, HIDDEN_ / 64), blk, 0, stream>>>(obuf, Wo, nullptr, out, M, HIDDEN_, HIDDEN_);
}

// Round 2
// 4146.827 us; speedup vs baseline: 1.4482x; 1.4482x over previous
//
#include <hip/hip_runtime.h>
#include <hip/hip_bf16.h>
#include <math.h>

#define H_ 16
#define HK_ 64
#define HV_ 64
#define HIDDEN_ 1024
#define BATCH_ 4
#define T_ 2048

__device__ __forceinline__ float wave_sum64(float v) {
  #pragma unroll
  for (int m = 32; m >= 1; m >>= 1) v += __shfl_xor(v, m, 64);
  return v;
}

__device__ __forceinline__ float sigmoidf_(float x) { return 1.f / (1.f + expf(-x)); }
__device__ __forceinline__ float siluf_(float x) { return x / (1.f + expf(-x)); }

// ---------------------------------------------------------------------------
// Simple f32 tiled GEMM: C[M,N] = A[M,K] @ B[K,N] (+ bias[N] if given)
// ---------------------------------------------------------------------------
__global__ __launch_bounds__(256) void gemm_f32(
    const float* __restrict__ A, const float* __restrict__ B,
    const float* __restrict__ bias, float* __restrict__ C,
    int M, int N, int K) {
  __shared__ float As[64][17];
  __shared__ float Bs[16][65];
  const int tx = threadIdx.x % 16;
  const int ty = threadIdx.x / 16;
  const int bm = blockIdx.x * 64;
  const int bn = blockIdx.y * 64;
  float acc[4][4] = {};
  for (int k0 = 0; k0 < K; k0 += 16) {
    #pragma unroll
    for (int i = 0; i < 4; i++) {
      int idx = threadIdx.x + i * 256;
      int m  = idx / 16, kk = idx % 16;
      As[m][kk] = A[(size_t)(bm + m) * K + (k0 + kk)];
      int kk2 = idx / 64, n = idx % 64;
      Bs[kk2][n] = (bn + n < N) ? B[(size_t)(k0 + kk2) * N + (bn + n)] : 0.f;
    }
    __syncthreads();
    #pragma unroll
    for (int kk = 0; kk < 16; kk++) {
      float a[4], b[4];
      #pragma unroll
      for (int i = 0; i < 4; i++) a[i] = As[ty * 4 + i][kk];
      #pragma unroll
      for (int j = 0; j < 4; j++) b[j] = Bs[kk][tx * 4 + j];
      #pragma unroll
      for (int i = 0; i < 4; i++)
        #pragma unroll
        for (int j = 0; j < 4; j++) acc[i][j] += a[i] * b[j];
    }
    __syncthreads();
  }
  #pragma unroll
  for (int i = 0; i < 4; i++) {
    #pragma unroll
    for (int j = 0; j < 4; j++) {
      int m = bm + ty * 4 + i, n = bn + tx * 4 + j;
      if (n < N) C[(size_t)m * N + n] = acc[i][j] + (bias ? bias[n] : 0.f);
    }
  }
}

// ---------------------------------------------------------------------------
// Gated delta-rule recurrence, 4 waves per (b,h) block.
// Wave w owns state rows k in [16w, 16w+16), lane = v index.
// Front-end specialization: wave0=q(conv+silu+norm), wave1=k, wave2=v(conv+silu),
// wave3=decay gate eg + beta. Broadcast scalars packed via float4 LDS reads.
// ---------------------------------------------------------------------------
__global__ __launch_bounds__(256) void recurrence4(
    const float* __restrict__ qhat, const float* __restrict__ khat,
    const float* __restrict__ vhat, const float* __restrict__ graw,
    const float* __restrict__ braw,
    const float* __restrict__ qcw, const float* __restrict__ qcb,
    const float* __restrict__ kcw, const float* __restrict__ kcb,
    const float* __restrict__ vcw, const float* __restrict__ vcb,
    const float* __restrict__ A_log, const float* __restrict__ dt_bias,
    float* __restrict__ o_out) {
  const int bh = blockIdx.x;            // 0 .. B*H-1
  const int b = bh / H_;
  const int h = bh % H_;
  const int wid = threadIdx.x >> 6;     // 0..3
  const int lane = threadIdx.x & 63;
  const int c = h * 64 + lane;

  __shared__ float qn_s[64], kn_s[64], eg_s[64], vv_s[64];
  __shared__ float kSp[4][64], oP[4][64];
  __shared__ float beta_s;

  // per-wave source + conv params
  const float* src = (wid == 0) ? qhat : (wid == 1) ? khat : (wid == 2) ? vhat : graw;
  float w0 = 0, w1 = 0, w2 = 0, w3 = 0, cb = 0, A = 0, dtb = 0;
  if (wid == 0) { w0 = qcw[c*4]; w1 = qcw[c*4+1]; w2 = qcw[c*4+2]; w3 = qcw[c*4+3]; cb = qcb[c]; }
  else if (wid == 1) { w0 = kcw[c*4]; w1 = kcw[c*4+1]; w2 = kcw[c*4+2]; w3 = kcw[c*4+3]; cb = kcb[c]; }
  else if (wid == 2) { w0 = vcw[c*4]; w1 = vcw[c*4+1]; w2 = vcw[c*4+2]; w3 = vcw[c*4+3]; cb = vcb[c]; }
  else { A = expf(A_log[h]); dtb = dt_bias[c]; }

  float S[16];
  #pragma unroll
  for (int i = 0; i < 16; i++) S[i] = 0.f;

  float x0 = 0, x1 = 0, x2 = 0;  // rolling causal window
  const size_t base = ((size_t)b * T_) * HIDDEN_ + c;
  const size_t bbase = ((size_t)b * T_) * H_ + h;

  float nx = src[base];
  float nbr = (wid == 3) ? braw[bbase] : 0.f;

  const int k0 = wid * 16;

  for (int t = 0; t < T_; t++) {
    float x3 = nx, br = nbr;
    if (t + 1 < T_) {
      nx = src[base + (size_t)(t + 1) * HIDDEN_];
      if (wid == 3) nbr = braw[bbase + (size_t)(t + 1) * H_];
    }

    if (wid < 3) {
      float val = cb + x0 * w0 + x1 * w1 + x2 * w2 + x3 * w3;
      x0 = x1; x1 = x2; x2 = x3;
      val = siluf_(val);
      if (wid == 0) {
        float s = wave_sum64(val * val);
        qn_s[lane] = val / (sqrtf(s) + 1e-6f) * 0.125f;   // HK^-0.5
      } else if (wid == 1) {
        float s = wave_sum64(val * val);
        kn_s[lane] = val / (sqrtf(s) + 1e-6f);
      } else {
        vv_s[lane] = val;
      }
    } else {
      float xg = x3 + dtb;
      float sp = (xg > 20.f) ? xg : log1pf(expf(xg));
      eg_s[lane] = expf(-A * sp);
      if (lane == 0) beta_s = sigmoidf_(br);
    }
    __syncthreads();  // A: front-end values visible

    // pass 1: decay + partial kS over this wave's 16 k-rows
    float kS = 0.f;
    #pragma unroll
    for (int ii = 0; ii < 4; ii++) {
      float4 eg4 = *(const float4*)&eg_s[k0 + ii * 4];
      float4 kn4 = *(const float4*)&kn_s[k0 + ii * 4];
      S[ii*4+0] *= eg4.x; kS += kn4.x * S[ii*4+0];
      S[ii*4+1] *= eg4.y; kS += kn4.y * S[ii*4+1];
      S[ii*4+2] *= eg4.z; kS += kn4.z * S[ii*4+2];
      S[ii*4+3] *= eg4.w; kS += kn4.w * S[ii*4+3];
    }
    kSp[wid][lane] = kS;
    float vv = vv_s[lane];
    float beta = beta_s;
    __syncthreads();  // B: partials visible

    float kSt = kSp[0][lane] + kSp[1][lane] + kSp[2][lane] + kSp[3][lane];
    float vupd = beta * (vv - kSt);

    // pass 2: rank-1 update + partial output
    float o = 0.f;
    #pragma unroll
    for (int ii = 0; ii < 4; ii++) {
      float4 kn4 = *(const float4*)&kn_s[k0 + ii * 4];
      float4 qn4 = *(const float4*)&qn_s[k0 + ii * 4];
      S[ii*4+0] += kn4.x * vupd; o += qn4.x * S[ii*4+0];
      S[ii*4+1] += kn4.y * vupd; o += qn4.y * S[ii*4+1];
      S[ii*4+2] += kn4.z * vupd; o += qn4.z * S[ii*4+2];
      S[ii*4+3] += kn4.w * vupd; o += qn4.w * S[ii*4+3];
    }
    oP[wid][lane] = o;
    __syncthreads();  // C: output partials visible

    if (wid == 0) {
      o_out[base + (size_t)t * HIDDEN_] =
          oP[0][lane] + oP[1][lane] + oP[2][lane] + oP[3][lane];
    }
  }
}

// ---------------------------------------------------------------------------
// RMS-norm over HV + weight + sigmoid(gate), in-place on o.
// ---------------------------------------------------------------------------
__global__ __launch_bounds__(256) void onorm_gate(
    float* __restrict__ o, const float* __restrict__ gate,
    const float* __restrict__ onw, int total_groups) {
  int g = blockIdx.x * (blockDim.x / 64) + threadIdx.x / 64;
  int lane = threadIdx.x % 64;
  if (g >= total_groups) return;
  size_t idx = (size_t)g * 64 + lane;
  float ov = o[idx];
  float ms = wave_sum64(ov * ov) * (1.f / 64.f);
  float r = rsqrtf(ms + 1e-5f);
  o[idx] = ov * r * onw[lane] * sigmoidf_(gate[idx]);
}

extern "C" void kernel_launch(void* const* d_in, const int* in_sizes, int n_in,
                              void* d_out, int out_size, void* d_ws, size_t ws_size,
                              hipStream_t stream) {
  const float* hs    = (const float*)d_in[0];
  const float* Wq    = (const float*)d_in[1];
  const float* Wk    = (const float*)d_in[2];
  const float* Wv    = (const float*)d_in[3];
  const float* qcw   = (const float*)d_in[4];
  const float* qcb   = (const float*)d_in[5];
  const float* kcw   = (const float*)d_in[6];
  const float* kcb   = (const float*)d_in[7];
  const float* vcw   = (const float*)d_in[8];
  const float* vcb   = (const float*)d_in[9];
  const float* Wf1   = (const float*)d_in[10];
  const float* Wf2   = (const float*)d_in[11];
  const float* Wb    = (const float*)d_in[12];
  const float* A_log = (const float*)d_in[13];
  const float* dtb   = (const float*)d_in[14];
  const float* Wg1   = (const float*)d_in[15];
  const float* Wg2   = (const float*)d_in[16];
  const float* bg2   = (const float*)d_in[17];
  const float* onw   = (const float*)d_in[18];
  const float* Wo    = (const float*)d_in[19];
  float* out = (float*)d_out;

  const int M = BATCH_ * T_;  // 8192
  char* ws = (char*)d_ws;
  const size_t SZ = (size_t)M * HIDDEN_ * sizeof(float);       // 32 MB
  const size_t SM = (size_t)M * HV_ * sizeof(float);           // 2 MB
  float* qhat = (float*)(ws);
  float* khat = (float*)(ws + SZ);
  float* vhat = (float*)(ws + 2 * SZ);
  float* graw = (float*)(ws + 3 * SZ);
  float* obuf = (float*)(ws + 4 * SZ);
  float* f1   = (float*)(ws + 5 * SZ);
  float* g1   = (float*)(ws + 5 * SZ + SM);
  float* braw = (float*)(ws + 5 * SZ + 2 * SM);
  float* gate = khat;  // reused after the recurrence consumes khat

  dim3 blk(256);
  gemm_f32<<<dim3(M / 64, HIDDEN_ / 64), blk, 0, stream>>>(hs, Wq, nullptr, qhat, M, HIDDEN_, HIDDEN_);
  gemm_f32<<<dim3(M / 64, HIDDEN_ / 64), blk, 0, stream>>>(hs, Wk, nullptr, khat, M, HIDDEN_, HIDDEN_);
  gemm_f32<<<dim3(M / 64, HIDDEN_ / 64), blk, 0, stream>>>(hs, Wv, nullptr, vhat, M, HIDDEN_, HIDDEN_);
  gemm_f32<<<dim3(M / 64, 1), blk, 0, stream>>>(hs, Wf1, nullptr, f1, M, HV_, HIDDEN_);
  gemm_f32<<<dim3(M / 64, 1), blk, 0, stream>>>(hs, Wg1, nullptr, g1, M, HV_, HIDDEN_);
  gemm_f32<<<dim3(M / 64, 1), blk, 0, stream>>>(hs, Wb, nullptr, braw, M, H_, HIDDEN_);
  gemm_f32<<<dim3(M / 64, HIDDEN_ / 64), blk, 0, stream>>>(f1, Wf2, nullptr, graw, M, HIDDEN_, HV_);

  recurrence4<<<dim3(BATCH_ * H_), dim3(256), 0, stream>>>(
      qhat, khat, vhat, graw, braw, qcw, qcb, kcw, kcb, vcw, vcb, A_log, dtb, obuf);

  gemm_f32<<<dim3(M / 64, HIDDEN_ / 64), blk, 0, stream>>>(g1, Wg2, bg2, gate, M, HIDDEN_, HV_);

  int groups = M * H_;
  onorm_gate<<<dim3((groups + 3) / 4), blk, 0, stream>>>(obuf, gate, onw, groups);

  gemm_f32<<<dim3(M / 64, HIDDEN_ / 64), blk, 0, stream>>>(obuf, Wo, nullptr, out, M, HIDDEN_, HIDDEN_);
}

// Round 3
// 3399.432 us; speedup vs baseline: 1.7666x; 1.2199x over previous
//
#include <hip/hip_runtime.h>
#include <hip/hip_bf16.h>
#include <math.h>

#define H_ 16
#define HK_ 64
#define HV_ 64
#define HIDDEN_ 1024
#define BATCH_ 4
#define T_ 2048
#define M_ (BATCH_ * T_)   // 8192

typedef __attribute__((ext_vector_type(8))) __bf16 bf16x8;
typedef __attribute__((ext_vector_type(4))) float f32x4;

__device__ __forceinline__ float wave_sum64(float v) {
  #pragma unroll
  for (int m = 32; m >= 1; m >>= 1) v += __shfl_xor(v, m, 64);
  return v;
}
__device__ __forceinline__ float sigmoidf_(float x) { return 1.f / (1.f + expf(-x)); }
__device__ __forceinline__ float siluf_(float x) { return x / (1.f + expf(-x)); }
__device__ __forceinline__ float bf2f(ushort u) {
  unsigned int x = ((unsigned int)u) << 16;
  return __builtin_bit_cast(float, x);
}
__device__ __forceinline__ ushort f2bf(float f) {   // RNE
  unsigned int x = __builtin_bit_cast(unsigned int, f);
  unsigned int r = (x + 0x7fffu + ((x >> 16) & 1u)) >> 16;
  return (ushort)r;
}

// ---------------------------------------------------------------------------
// Split-pack A: f32 [M,K] (row stride inStride) -> bf16 [M,3K] laid out
// [hi | lo | hi] along K. Coalesced reads and writes (k fastest).
// ---------------------------------------------------------------------------
__global__ __launch_bounds__(256) void split_pack_A(
    const float* __restrict__ in, int inStride, int K, int M,
    ushort* __restrict__ out) {
  size_t tid = (size_t)blockIdx.x * 256 + threadIdx.x;
  if (tid >= (size_t)M * K) return;
  int k = (int)(tid % K);
  size_t m = tid / K;
  float x = in[m * inStride + k];
  ushort hi = f2bf(x);
  float rem = x - bf2f(hi);
  ushort lo = f2bf(rem);
  size_t o = m * (size_t)(3 * K);
  out[o + k] = hi;
  out[o + K + k] = lo;
  out[o + 2 * K + k] = hi;
}

// ---------------------------------------------------------------------------
// Pack weight W [K,N] f32 -> transposed split bf16 Bt rows: out[n][k'] with
// k' blocks [hi | hi | lo] (so that A'[h|l|h] @ B'[h;h;l] = AhBh+AlBh+AhBl).
// out points at the first row for this weight; rowStride = 3*K_total of GEMM.
// ---------------------------------------------------------------------------
__global__ __launch_bounds__(256) void pack_w3t(
    const float* __restrict__ W, int K, int N,
    ushort* __restrict__ out, int rowStride) {
  size_t tid = (size_t)blockIdx.x * 256 + threadIdx.x;
  if (tid >= (size_t)K * N) return;
  int k = (int)(tid % K);
  size_t n = tid / K;
  float x = W[(size_t)k * N + n];
  ushort hi = f2bf(x);
  float rem = x - bf2f(hi);
  ushort lo = f2bf(rem);
  size_t o = n * (size_t)rowStride;
  out[o + k] = hi;
  out[o + K + k] = hi;
  out[o + 2 * K + k] = lo;
}

// ---------------------------------------------------------------------------
// bf16 MFMA GEMM: C[M,N] = A[M,K] @ Bt[N,K]^T (+bias). 128x128 tile, 4 waves
// (2x2), each wave 64x64 via 4x4 fragments of 16x16x32 MFMA.
// Fragment layouts (gfx950, guide-verified): A[l&15][(l>>4)*8+i],
// B[(l>>4)*8+i][l&15], D: col=l&15, row=(l>>4)*4+r.
// ---------------------------------------------------------------------------
template <typename OutT>
__global__ __launch_bounds__(256) void gemm_split(
    const ushort* __restrict__ A, const ushort* __restrict__ Bt,
    const float* __restrict__ bias, OutT* __restrict__ C,
    int M, int N, int K) {
  __shared__ ushort As[128][40];   // +8 pad: conflict-free b128 reads
  __shared__ ushort Bs[128][40];
  const int tid = threadIdx.x;
  const int bm = blockIdx.x * 128, bn = blockIdx.y * 128;
  const int wid = tid >> 6, lane = tid & 63;
  const int wm = (wid >> 1) * 64, wn = (wid & 1) * 64;
  const int fr = lane & 15, fq = lane >> 4;
  const int sm = tid >> 1, skk = (tid & 1) * 16;   // staging: 32B per thread

  f32x4 acc[4][4] = {};

  for (int k0 = 0; k0 < K; k0 += 32) {
    const ushort* ga = A + (size_t)(bm + sm) * K + k0 + skk;
    const ushort* gb = Bt + (size_t)(bn + sm) * K + k0 + skk;
    uint4 a0 = *(const uint4*)ga;
    uint4 a1 = *(const uint4*)(ga + 8);
    uint4 b0 = *(const uint4*)gb;
    uint4 b1 = *(const uint4*)(gb + 8);
    *(uint4*)&As[sm][skk] = a0;
    *(uint4*)&As[sm][skk + 8] = a1;
    *(uint4*)&Bs[sm][skk] = b0;
    *(uint4*)&Bs[sm][skk + 8] = b1;
    __syncthreads();

    bf16x8 af[4], bfr[4];
    #pragma unroll
    for (int i = 0; i < 4; i++) af[i] = *(const bf16x8*)&As[wm + i * 16 + fr][fq * 8];
    #pragma unroll
    for (int j = 0; j < 4; j++) bfr[j] = *(const bf16x8*)&Bs[wn + j * 16 + fr][fq * 8];
    #pragma unroll
    for (int i = 0; i < 4; i++)
      #pragma unroll
      for (int j = 0; j < 4; j++)
        acc[i][j] = __builtin_amdgcn_mfma_f32_16x16x32_bf16(af[i], bfr[j], acc[i][j], 0, 0, 0);
    __syncthreads();
  }

  #pragma unroll
  for (int i = 0; i < 4; i++) {
    #pragma unroll
    for (int j = 0; j < 4; j++) {
      int col = bn + wn + j * 16 + fr;
      float bv = bias ? bias[col] : 0.f;
      #pragma unroll
      for (int r = 0; r < 4; r++) {
        int row = bm + wm + i * 16 + fq * 4 + r;
        float v = acc[i][j][r] + bv;
        if constexpr (sizeof(OutT) == 2) {
          ((ushort*)C)[(size_t)row * N + col] = f2bf(v);
        } else {
          ((float*)C)[(size_t)row * N + col] = v;
        }
      }
    }
  }
}

// ---------------------------------------------------------------------------
// Gated delta-rule recurrence, v-split: grid (B*H, 4), 1 wave per block.
// Block (bh, vq) owns v-columns [16vq, 16vq+16). lane = kq*16+vi: lane holds
// S[k=16kq..16kq+15][v=16vq+vi]. Frontend (conv+silu+norms+gate) computed by
// all lanes at channel c=h*64+lane; cross-k reductions via wave shuffles;
// per-k scalars shared via same-wave LDS (double-buffered, 1 barrier/step).
// ---------------------------------------------------------------------------
__global__ __launch_bounds__(64) void recurrence_v(
    const ushort* __restrict__ qkv,    // [M,3072] bf16: q|k|v
    const ushort* __restrict__ graw,   // [M,1024] bf16
    const float* __restrict__ f1g1b,   // [M,256] f32, braw at col 128+h
    const float* __restrict__ qcw, const float* __restrict__ qcb,
    const float* __restrict__ kcw, const float* __restrict__ kcb,
    const float* __restrict__ vcw, const float* __restrict__ vcb,
    const float* __restrict__ A_log, const float* __restrict__ dt_bias,
    float* __restrict__ o_out) {
  const int bh = blockIdx.x;
  const int vq = blockIdx.y;
  const int b = bh >> 4, h = bh & 15;
  const int lane = threadIdx.x;
  const int kq = lane >> 4, vi = lane & 15;
  const int v0 = vq * 16;
  const int c = h * 64 + lane;

  const float A = expf(A_log[h]);
  const float dtb = dt_bias[c];
  float qw0 = qcw[c*4], qw1 = qcw[c*4+1], qw2 = qcw[c*4+2], qw3 = qcw[c*4+3], qb = qcb[c];
  float kw0 = kcw[c*4], kw1 = kcw[c*4+1], kw2 = kcw[c*4+2], kw3 = kcw[c*4+3], kb = kcb[c];
  float vw0 = vcw[c*4], vw1 = vcw[c*4+1], vw2 = vcw[c*4+2], vw3 = vcw[c*4+3], vb = vcb[c];

  float S[16];
  #pragma unroll
  for (int i = 0; i < 16; i++) S[i] = 0.f;

  __shared__ float kn_s[2][64], qn_s[2][64], eg_s[2][64];

  float xq0 = 0, xq1 = 0, xq2 = 0;
  float xk0 = 0, xk1 = 0, xk2 = 0;
  float xv0 = 0, xv1 = 0, xv2 = 0;

  const size_t rowbase = (size_t)b * T_;
  // prefetch t=0
  ushort nq = qkv[rowbase * 3072 + c];
  ushort nk = qkv[rowbase * 3072 + 1024 + c];
  ushort nv = qkv[rowbase * 3072 + 2048 + c];
  ushort ng = graw[rowbase * 1024 + c];
  float nbr = f1g1b[rowbase * 256 + 128 + h];

  for (int t = 0; t < T_; t++) {
    float xq3 = bf2f(nq), xk3 = bf2f(nk), xv3 = bf2f(nv);
    float gr = bf2f(ng), br = nbr;
    if (t + 1 < T_) {
      size_t row = rowbase + t + 1;
      nq = qkv[row * 3072 + c];
      nk = qkv[row * 3072 + 1024 + c];
      nv = qkv[row * 3072 + 2048 + c];
      ng = graw[row * 1024 + c];
      nbr = f1g1b[row * 256 + 128 + h];
    }

    float qv = qb + xq0 * qw0 + xq1 * qw1 + xq2 * qw2 + xq3 * qw3;
    float kv = kb + xk0 * kw0 + xk1 * kw1 + xk2 * kw2 + xk3 * kw3;
    float vv = vb + xv0 * vw0 + xv1 * vw1 + xv2 * vw2 + xv3 * vw3;
    xq0 = xq1; xq1 = xq2; xq2 = xq3;
    xk0 = xk1; xk1 = xk2; xk2 = xk3;
    xv0 = xv1; xv1 = xv2; xv2 = xv3;
    qv = siluf_(qv); kv = siluf_(kv); vv = siluf_(vv);

    float sq = wave_sum64(qv * qv);
    float sk = wave_sum64(kv * kv);
    float qn = qv / (sqrtf(sq) + 1e-6f) * 0.125f;
    float kn = kv / (sqrtf(sk) + 1e-6f);
    float xg = gr + dtb;
    float sp = (xg > 20.f) ? xg : log1pf(expf(xg));
    float eg = expf(-A * sp);

    const int tb = t & 1;
    kn_s[tb][lane] = kn; qn_s[tb][lane] = qn; eg_s[tb][lane] = eg;
    float vvv = __shfl(vv, v0 + vi, 64);
    float beta = sigmoidf_(br);
    __syncthreads();

    float kS = 0.f;
    #pragma unroll
    for (int ii = 0; ii < 4; ii++) {
      float4 eg4 = *(const float4*)&eg_s[tb][kq * 16 + ii * 4];
      float4 kn4 = *(const float4*)&kn_s[tb][kq * 16 + ii * 4];
      S[ii*4+0] *= eg4.x; kS += kn4.x * S[ii*4+0];
      S[ii*4+1] *= eg4.y; kS += kn4.y * S[ii*4+1];
      S[ii*4+2] *= eg4.z; kS += kn4.z * S[ii*4+2];
      S[ii*4+3] *= eg4.w; kS += kn4.w * S[ii*4+3];
    }
    kS += __shfl_xor(kS, 16, 64);
    kS += __shfl_xor(kS, 32, 64);
    float vupd = beta * (vvv - kS);

    float o = 0.f;
    #pragma unroll
    for (int ii = 0; ii < 4; ii++) {
      float4 kn4 = *(const float4*)&kn_s[tb][kq * 16 + ii * 4];
      float4 qn4 = *(const float4*)&qn_s[tb][kq * 16 + ii * 4];
      S[ii*4+0] += kn4.x * vupd; o += qn4.x * S[ii*4+0];
      S[ii*4+1] += kn4.y * vupd; o += qn4.y * S[ii*4+1];
      S[ii*4+2] += kn4.z * vupd; o += qn4.z * S[ii*4+2];
      S[ii*4+3] += kn4.w * vupd; o += qn4.w * S[ii*4+3];
    }
    o += __shfl_xor(o, 16, 64);
    o += __shfl_xor(o, 32, 64);
    if (kq == 0) {
      o_out[(rowbase + t) * 1024 + h * 64 + v0 + vi] = o;
    }
  }
}

// ---------------------------------------------------------------------------
// RMS-norm over HV + weight + sigmoid(gate), in-place on o.
// ---------------------------------------------------------------------------
__global__ __launch_bounds__(256) void onorm_gate(
    float* __restrict__ o, const float* __restrict__ gate,
    const float* __restrict__ onw, int total_groups) {
  int g = blockIdx.x * (blockDim.x / 64) + threadIdx.x / 64;
  int lane = threadIdx.x % 64;
  if (g >= total_groups) return;
  size_t idx = (size_t)g * 64 + lane;
  float ov = o[idx];
  float ms = wave_sum64(ov * ov) * (1.f / 64.f);
  float r = rsqrtf(ms + 1e-5f);
  o[idx] = ov * r * onw[lane] * sigmoidf_(gate[idx]);
}

extern "C" void kernel_launch(void* const* d_in, const int* in_sizes, int n_in,
                              void* d_out, int out_size, void* d_ws, size_t ws_size,
                              hipStream_t stream) {
  const float* hs    = (const float*)d_in[0];
  const float* Wq    = (const float*)d_in[1];
  const float* Wk    = (const float*)d_in[2];
  const float* Wv    = (const float*)d_in[3];
  const float* qcw   = (const float*)d_in[4];
  const float* qcb   = (const float*)d_in[5];
  const float* kcw   = (const float*)d_in[6];
  const float* kcb   = (const float*)d_in[7];
  const float* vcw   = (const float*)d_in[8];
  const float* vcb   = (const float*)d_in[9];
  const float* Wf1   = (const float*)d_in[10];
  const float* Wf2   = (const float*)d_in[11];
  const float* Wb    = (const float*)d_in[12];
  const float* A_log = (const float*)d_in[13];
  const float* dtb   = (const float*)d_in[14];
  const float* Wg1   = (const float*)d_in[15];
  const float* Wg2   = (const float*)d_in[16];
  const float* bg2   = (const float*)d_in[17];
  const float* onw   = (const float*)d_in[18];
  const float* Wo    = (const float*)d_in[19];
  float* out = (float*)d_out;

  char* ws = (char*)d_ws;
  // Region layout (bytes):
  ushort* hs3    = (ushort*)(ws);                       // [8192,3072] bf16, 48MB; later obuf3
  ushort* qkvhat = (ushort*)(ws + 50331648);            // [8192,3072] bf16, 48MB; later gate f32 (32MB)
  ushort* grawB  = (ushort*)(ws + 100663296);           // [8192,1024] bf16, 16MB
  float*  obuf   = (float*)(ws + 117440512);            // [8192,1024] f32, 32MB
  char*   R4     = ws + 150994944;                      // 18MB pool
  ushort* Wqkv3  = (ushort*)R4;                         // [3072,3072] bf16, 18MB
  ushort* Wfgb3  = (ushort*)R4;                         // [256,3072] bf16, 1.5MB (after qkv GEMM)
  float*  f1g1b  = (float*)(R4 + 1572864);              // [8192,256] f32, 8MB
  ushort* f1_3   = (ushort*)(R4 + 9961472);             // [8192,192] bf16, 3MB
  ushort* g1_3   = (ushort*)(R4 + 13107200);            // [8192,192] bf16, 3MB
  ushort* Wf2_3  = (ushort*)(R4 + 16252928);            // [1024,192] bf16
  ushort* Wg2_3  = (ushort*)(R4 + 16646144);            // [1024,192] bf16
  ushort* Wo3    = (ushort*)R4;                         // [1024,3072] bf16, 6MB (after gate GEMM)
  ushort* obuf3  = hs3;                                 // [8192,3072] bf16
  float*  gate   = (float*)qkvhat;                      // [8192,1024] f32

  dim3 blk(256);
  const int PK = 1024 * 1024;  // elements per 1024x1024 pack

  // 1. split hidden_states -> hs3
  split_pack_A<<<dim3((M_ * 1024) / 256), blk, 0, stream>>>(hs, 1024, 1024, M_, hs3);
  // 2. pack Wq/Wk/Wv -> Wqkv3T rows [0,1024,2048)
  pack_w3t<<<dim3(PK / 256), blk, 0, stream>>>(Wq, 1024, 1024, Wqkv3, 3072);
  pack_w3t<<<dim3(PK / 256), blk, 0, stream>>>(Wk, 1024, 1024, Wqkv3 + (size_t)1024 * 3072, 3072);
  pack_w3t<<<dim3(PK / 256), blk, 0, stream>>>(Wv, 1024, 1024, Wqkv3 + (size_t)2048 * 3072, 3072);
  // 3. qkv projection GEMM -> qkvhat bf16
  gemm_split<ushort><<<dim3(M_ / 128, 3072 / 128), blk, 0, stream>>>(
      hs3, Wqkv3, nullptr, qkvhat, M_, 3072, 3072);
  // 4. pack Wf1|Wg1|Wb -> Wfgb3T (reuses Wqkv3 space), pad rows zeroed
  hipMemsetAsync(Wfgb3, 0, (size_t)256 * 3072 * 2, stream);
  pack_w3t<<<dim3((1024 * 64) / 256), blk, 0, stream>>>(Wf1, 1024, 64, Wfgb3, 3072);
  pack_w3t<<<dim3((1024 * 64) / 256), blk, 0, stream>>>(Wg1, 1024, 64, Wfgb3 + (size_t)64 * 3072, 3072);
  pack_w3t<<<dim3((1024 * 16) / 256), blk, 0, stream>>>(Wb, 1024, 16, Wfgb3 + (size_t)128 * 3072, 3072);
  // 5. f1|g1|braw GEMM -> f1g1b f32 [8192,256]
  gemm_split<float><<<dim3(M_ / 128, 2), blk, 0, stream>>>(
      hs3, Wfgb3, nullptr, f1g1b, M_, 256, 3072);
  // 6. split f1, g1 (K=64, stride 256)
  split_pack_A<<<dim3((M_ * 64) / 256), blk, 0, stream>>>(f1g1b, 256, 64, M_, f1_3);
  split_pack_A<<<dim3((M_ * 64) / 256), blk, 0, stream>>>(f1g1b + 64, 256, 64, M_, g1_3);
  // 7. graw = f1 @ Wf2 -> bf16
  pack_w3t<<<dim3((64 * 1024) / 256), blk, 0, stream>>>(Wf2, 64, 1024, Wf2_3, 192);
  gemm_split<ushort><<<dim3(M_ / 128, 1024 / 128), blk, 0, stream>>>(
      f1_3, Wf2_3, nullptr, grawB, M_, 1024, 192);
  // 8. recurrence
  recurrence_v<<<dim3(BATCH_ * H_, 4), dim3(64), 0, stream>>>(
      qkvhat, grawB, f1g1b, qcw, qcb, kcw, kcb, vcw, vcb, A_log, dtb, obuf);
  // 9. gate = g1 @ Wg2 + bg2 -> f32 (aliases qkvhat, dead after recurrence)
  pack_w3t<<<dim3((64 * 1024) / 256), blk, 0, stream>>>(Wg2, 64, 1024, Wg2_3, 192);
  gemm_split<float><<<dim3(M_ / 128, 1024 / 128), blk, 0, stream>>>(
      g1_3, Wg2_3, bg2, gate, M_, 1024, 192);
  // 10. RMS-norm + gating in-place on obuf
  int groups = M_ * H_;
  onorm_gate<<<dim3((groups + 3) / 4), blk, 0, stream>>>(obuf, gate, onw, groups);
  // 11. out = obuf @ Wo
  split_pack_A<<<dim3((M_ * 1024) / 256), blk, 0, stream>>>(obuf, 1024, 1024, M_, obuf3);
  pack_w3t<<<dim3(PK / 256), blk, 0, stream>>>(Wo, 1024, 1024, Wo3, 3072);
  gemm_split<float><<<dim3(M_ / 128, 1024 / 128), blk, 0, stream>>>(
      obuf3, Wo3, nullptr, out, M_, 1024, 3072);
}